// Round 1
// baseline (7088.033 us; speedup 1.0000x reference)
//
#include <hip/hip_runtime.h>

#define NN 512
#define NR 511
#define NB 64
#define BATCH 256
#define NMAT 257
#define EPSF 1e-7f

// ---------------- block reduce (512 threads) ----------------
__device__ __forceinline__ float block_reduce_sum_512(float v, float* red) {
#pragma unroll
  for (int off = 32; off > 0; off >>= 1) v += __shfl_down(v, off, 64);
  int tid = threadIdx.x;
  if ((tid & 63) == 0) red[tid >> 6] = v;
  __syncthreads();
  float s = 0.f;
#pragma unroll
  for (int w = 0; w < 8; ++w) s += red[w];
  return s;
}

// ---------------- V = softmax(V_compress, axis=1) ----------------
__global__ void k_softmaxV(const float* __restrict__ Vc, float* __restrict__ V) {
  int i = threadIdx.x;  // 512 threads, 1 block
  float v0 = Vc[i * 4 + 0], v1 = Vc[i * 4 + 1], v2 = Vc[i * 4 + 2], v3 = Vc[i * 4 + 3];
  float mx = fmaxf(fmaxf(v0, v1), fmaxf(v2, v3));
  float e0 = expf(v0 - mx), e1 = expf(v1 - mx), e2 = expf(v2 - mx), e3 = expf(v3 - mx);
  float s = e0 + e1 + e2 + e3;
  V[i * 4 + 0] = e0 / s; V[i * 4 + 1] = e1 / s; V[i * 4 + 2] = e2 / s; V[i * 4 + 3] = e3 / s;
}

// ---------------- Ws[i][j] = sym tril sigmoid ----------------
__global__ void k_Ws(const float* __restrict__ W, float* __restrict__ Ws) {
  int i = blockIdx.x, j = threadIdx.x;
  float v = 0.f;
  if (i != j) {
    int hi = i > j ? i : j, lo = i > j ? j : i;
    float wv = W[hi * NN + lo];
    v = 1.f / (1.f + expf(-wv));
  }
  Ws[i * NN + j] = v;
}

// ---------------- E sinkhorn: per (i,j) independent 4x4 ----------------
__global__ void k_E(const float* __restrict__ Ec, const float* __restrict__ V,
                    float* __restrict__ E) {
  int idx = blockIdx.x * blockDim.x + threadIdx.x;  // i*512 + j
  if (idx >= NN * NN) return;
  int i = idx >> 9, j = idx & 511;
  float e[16];
  const float* src = Ec + (size_t)idx * 16;
#pragma unroll
  for (int t = 0; t < 16; ++t) e[t] = expf(src[t]);
  float tot = 0.f;
#pragma unroll
  for (int t = 0; t < 16; ++t) tot += e[t];
  float rt = 1.f / tot;
#pragma unroll
  for (int t = 0; t < 16; ++t) e[t] *= rt;
  float Vi[4], Vj[4];
#pragma unroll
  for (int a = 0; a < 4; ++a) { Vi[a] = V[i * 4 + a]; Vj[a] = V[j * 4 + a]; }
#pragma unroll
  for (int it = 0; it < 2; ++it) {
#pragma unroll
    for (int a = 0; a < 4; ++a) {
      float rs = e[a * 4 + 0] + e[a * 4 + 1] + e[a * 4 + 2] + e[a * 4 + 3];
      float sc = Vi[a] / rs;
#pragma unroll
      for (int b = 0; b < 4; ++b) e[a * 4 + b] *= sc;
    }
#pragma unroll
    for (int b = 0; b < 4; ++b) {
      float cs = e[0 + b] + e[4 + b] + e[8 + b] + e[12 + b];
      float sc = Vj[b] / cs;
#pragma unroll
      for (int a = 0; a < 4; ++a) e[a * 4 + b] *= sc;
    }
    float t2 = 0.f;
#pragma unroll
    for (int t = 0; t < 16; ++t) t2 += e[t];
    float rt2 = 1.f / t2;
#pragma unroll
    for (int t = 0; t < 16; ++t) e[t] *= rt2;
  }
  float* dst = E + (size_t)idx * 16;
  bool diag = (i == j);
#pragma unroll
  for (int t = 0; t < 16; ++t) {
    float v = diag ? 0.f : e[t];
    dst[t] = fminf(fmaxf(v, 0.f), 1.f);
  }
}

// ---------------- Pr + sum log(Pr+EPS) ----------------
__global__ __launch_bounds__(512)
void k_Pr(const int* __restrict__ x, const float* __restrict__ V,
          float* __restrict__ Pr, float* __restrict__ logPr) {
  __shared__ float red[8];
  int b = blockIdx.x, i = threadIdx.x;
  int xi = x[b * NN + i];
  float pr = V[i * 4 + xi];
  Pr[b * NN + i] = pr;
  float s = block_reduce_sum_512(logf(pr + EPSF), red);
  if (i == 0) logPr[b] = s;
}

// ---------------- build padded 512x512 Laplacian submatrix ----------------
// rows/cols 0..510 = Lap[1:,1:]+EPS ; row/col 511 = unit padding (det unchanged)
__global__ __launch_bounds__(512)
void k_build(const int* __restrict__ x, const float* __restrict__ Ws,
             const float* __restrict__ E, const float* __restrict__ Pr,
             float* __restrict__ mats, int m0) {
  __shared__ float red[8];
  int slot = blockIdx.y;
  int m = m0 + slot;
  float* A = mats + (size_t)slot * NN * NN;
  int r = blockIdx.x;   // matrix row 0..511
  int j = threadIdx.x;  // original column 0..511
  if (r == NR) {
    A[(size_t)NR * NN + j] = (j == NR) ? 1.f : 0.f;
    return;
  }
  int i = r + 1;  // original row
  float ws = Ws[i * NN + j];
  float wp;
  if (m < BATCH) {
    int xi = x[m * NN + i];
    int xj = x[m * NN + j];
    float e = E[((((size_t)i << 9) + j) << 4) + (xi << 2) + xj];
    float pij = Pr[m * NN + i] * Pr[m * NN + j];
    wp = ws * e / pij;   // ws==0 on diagonal -> wp==0
  } else {
    wp = ws;             // L_0 matrix
  }
  float rowsum = block_reduce_sum_512(wp, red);
  if (j >= 1) A[(size_t)r * NN + (j - 1)] = -wp + ((j == i) ? rowsum : 0.f) + EPSF;
  else        A[(size_t)r * NN + NR] = 0.f;
}

// ---------------- panel factorization (unpivoted, rows in registers) ------
__global__ __launch_bounds__(512)
void k_panel(float* __restrict__ mats, float* __restrict__ ld, int m0, int p) {
  __shared__ float Pv[64 * 64];  // pivot rows (U11 rows)
  int slot = blockIdx.x;
  float* A = mats + (size_t)slot * NN * NN;
  int k0 = p * NB;
  int m = NN - k0;
  int tid = threadIdx.x;
  bool own = tid < m;
  float* myrow = A + (size_t)(k0 + tid) * NN + k0;
  float rr[64];
  if (own) {
#pragma unroll
    for (int c = 0; c < 64; ++c) rr[c] = myrow[c];
  }
  if (tid == 0) {
#pragma unroll
    for (int c = 0; c < 64; ++c) Pv[c] = rr[c];
  }
  __syncthreads();
#pragma unroll
  for (int s = 0; s < 64; ++s) {
    float piv = Pv[s * 64 + s];
    float rinv = 1.f / piv;
    if (own && tid > s) {
      float l = rr[s] * rinv;
      rr[s] = l;  // store multiplier (LU-packed)
#pragma unroll
      for (int c = 0; c < 64; ++c)
        if (c > s) rr[c] = fmaf(-l, Pv[s * 64 + c], rr[c]);
    }
    if (s < 63 && tid == s + 1) {
#pragma unroll
      for (int c = 0; c < 64; ++c) Pv[(s + 1) * 64 + c] = rr[c];
    }
    __syncthreads();
  }
  if (own) {
#pragma unroll
    for (int c = 0; c < 64; ++c) myrow[c] = rr[c];
  }
  // partial logdet from pivots (all positive by diagonal dominance)
  float lg = 0.f;
  if (tid < 64) lg = logf(Pv[tid * 64 + tid]);
#pragma unroll
  for (int off = 32; off > 0; off >>= 1) lg += __shfl_down(lg, off, 64);
  if (tid == 0) {
    int gi = m0 + slot;
    if (p == 0) ld[gi] = lg;
    else        ld[gi] += lg;
  }
}

// ---------------- U12 = L11^{-1} A12 (forward substitution) ----------------
__global__ __launch_bounds__(512)
void k_u12(float* __restrict__ mats, int p) {
  __shared__ float L11[64 * 65];
  int slot = blockIdx.x;
  float* A = mats + (size_t)slot * NN * NN;
  int k0 = p * NB;
  int w = NN - k0 - NB;
  if (w <= 0) return;
  int tid = threadIdx.x;
  for (int idx = tid; idx < 4096; idx += 512) {
    int t = idx >> 6, c = idx & 63;
    L11[t * 65 + c] = A[(size_t)(k0 + t) * NN + k0 + c];
  }
  __syncthreads();
  int lane = tid & 63;
  bool act = tid < w;
  int col = k0 + NB + (act ? tid : 0);  // clamped: loads stay in-bounds
  float a[64];
#pragma unroll
  for (int t = 0; t < 64; ++t) a[t] = A[(size_t)(k0 + t) * NN + col];
#pragma unroll
  for (int s = 0; s < 64; ++s) {
    float colv = L11[lane * 65 + s];  // lane l holds L11[l][s]
    float as = a[s];
#pragma unroll
    for (int t = s + 1; t < 64; ++t) {
      float lv = __int_as_float(__builtin_amdgcn_readlane(__float_as_int(colv), t));
      a[t] = fmaf(-lv, as, a[t]);
    }
  }
  if (act) {
#pragma unroll
    for (int t = 0; t < 64; ++t) A[(size_t)(k0 + t) * NN + col] = a[t];
  }
}

// ---------------- trailing update A22 -= L21 * U12 ----------------
// grid (nt, nt, count), 256 threads, 128x128 tile, k = 64
__global__ __launch_bounds__(256)
void k_gemm(float* __restrict__ mats, int p) {
  __shared__ float At[128 * 65];  // L21 tile, [r][kk], stride 65 (conflict-free col reads)
  int k0 = p * NB;
  int w = NN - k0 - NB;
  float* A = mats + (size_t)blockIdx.z * NN * NN;
  int rb = blockIdx.x * 128, cb = blockIdx.y * 128;
  int tid = threadIdx.x;
#pragma unroll
  for (int it = 0; it < 32; ++it) {
    int idx = tid + it * 256;
    int r = idx >> 6, kk = idx & 63;
    int gr = rb + r;
    float v = 0.f;
    if (gr < w) v = A[(size_t)(k0 + NB + gr) * NN + k0 + kk];
    At[r * 65 + kk] = v;
  }
  __syncthreads();
  int ty = tid >> 4, tx = tid & 15;
  int r0 = ty * 8, c0 = tx * 8;
  int gc0 = k0 + NB + cb + c0;
  bool cok = (cb + c0) < w;  // w % 64 == 0, c0 % 8 == 0 -> whole 8-col group in or out
  float acc[8][8];
#pragma unroll
  for (int q = 0; q < 8; ++q)
#pragma unroll
    for (int u = 0; u < 8; ++u) acc[q][u] = 0.f;
#pragma unroll 4
  for (int kk = 0; kk < 64; ++kk) {
    float la[8];
#pragma unroll
    for (int q = 0; q < 8; ++q) la[q] = At[(r0 + q) * 65 + kk];
    float lb[8];
    if (cok) {
      float4 b0 = *(const float4*)&A[(size_t)(k0 + kk) * NN + gc0];
      float4 b1 = *(const float4*)&A[(size_t)(k0 + kk) * NN + gc0 + 4];
      lb[0] = b0.x; lb[1] = b0.y; lb[2] = b0.z; lb[3] = b0.w;
      lb[4] = b1.x; lb[5] = b1.y; lb[6] = b1.z; lb[7] = b1.w;
    } else {
#pragma unroll
      for (int u = 0; u < 8; ++u) lb[u] = 0.f;
    }
#pragma unroll
    for (int q = 0; q < 8; ++q)
#pragma unroll
      for (int u = 0; u < 8; ++u) acc[q][u] = fmaf(la[q], lb[u], acc[q][u]);
  }
  if (!cok) return;
#pragma unroll
  for (int q = 0; q < 8; ++q) {
    int gr = rb + r0 + q;
    if (gr < w) {
      float* dst = &A[(size_t)(k0 + NB + gr) * NN + gc0];
      float4 v0 = *(const float4*)dst;
      float4 v1 = *(const float4*)(dst + 4);
      v0.x -= acc[q][0]; v0.y -= acc[q][1]; v0.z -= acc[q][2]; v0.w -= acc[q][3];
      v1.x -= acc[q][4]; v1.y -= acc[q][5]; v1.z -= acc[q][6]; v1.w -= acc[q][7];
      *(float4*)dst = v0;
      *(float4*)(dst + 4) = v1;
    }
  }
}

// ---------------- final combine ----------------
__global__ void k_y(const float* __restrict__ logPr, const float* __restrict__ ld,
                    float* __restrict__ y) {
  int b = threadIdx.x;
  if (b < BATCH) y[b] = logPr[b] + ld[b] - ld[BATCH];
}

extern "C" void kernel_launch(void* const* d_in, const int* in_sizes, int n_in,
                              void* d_out, int out_size, void* d_ws, size_t ws_size,
                              hipStream_t stream) {
  const int* x = (const int*)d_in[0];
  const float* W = (const float*)d_in[1];
  const float* Vc = (const float*)d_in[2];
  const float* Ec = (const float*)d_in[3];
  float* out = (float*)d_out;

  char* ws = (char*)d_ws;
  size_t off = 0;
  auto alloc = [&](size_t bytes) -> void* {
    void* pp = ws + off;
    off = (off + bytes + 255) & ~(size_t)255;
    return pp;
  };
  float* V     = (float*)alloc((size_t)NN * 4 * 4);
  float* Wsbuf = (float*)alloc((size_t)NN * NN * 4);
  float* Pr    = (float*)alloc((size_t)BATCH * NN * 4);
  float* logPr = (float*)alloc((size_t)BATCH * 4);
  float* ld    = (float*)alloc((size_t)NMAT * 4);
  float* E     = (float*)alloc((size_t)NN * NN * 16 * 4);
  size_t per_mat = (size_t)NN * NN * 4;
  size_t remain = ws_size > off ? ws_size - off : 0;
  int cap = (int)(remain / per_mat);
  if (cap > NMAT) cap = NMAT;
  if (cap < 1) cap = 1;
  float* mats = (float*)(ws + off);

  k_softmaxV<<<1, 512, 0, stream>>>(Vc, V);
  k_Ws<<<NN, NN, 0, stream>>>(W, Wsbuf);
  k_E<<<(NN * NN) / 256, 256, 0, stream>>>(Ec, V, E);
  k_Pr<<<BATCH, NN, 0, stream>>>(x, V, Pr, logPr);

  for (int m0 = 0; m0 < NMAT; m0 += cap) {
    int cnt = NMAT - m0 < cap ? NMAT - m0 : cap;
    dim3 gb(NN, cnt);
    k_build<<<gb, NN, 0, stream>>>(x, Wsbuf, E, Pr, mats, m0);
    for (int p = 0; p < 8; ++p) {
      k_panel<<<cnt, NN, 0, stream>>>(mats, ld, m0, p);
      int w = NN - p * NB - NB;
      if (w > 0) {
        k_u12<<<cnt, NN, 0, stream>>>(mats, p);
        int nt = (w + 127) / 128;
        dim3 gg(nt, nt, cnt);
        k_gemm<<<gg, 256, 0, stream>>>(mats, p);
      }
    }
  }
  k_y<<<1, 256, 0, stream>>>(logPr, ld, out);
}

// Round 2
// 2028.116 us; speedup vs baseline: 3.4949x; 3.4949x over previous
//
#include <hip/hip_runtime.h>

#define NN 512
#define NR 511
#define NB 64
#define BATCH 256
#define NMAT 257
#define EPSF 1e-7f
#define PS 516  // panel LDS column stride (floats): mult of 4 (float4 align), 516%32=4 avoids worst banking

// ---------------- block reduce (512 threads) ----------------
__device__ __forceinline__ float block_reduce_sum_512(float v, float* red) {
#pragma unroll
  for (int off = 32; off > 0; off >>= 1) v += __shfl_down(v, off, 64);
  int tid = threadIdx.x;
  if ((tid & 63) == 0) red[tid >> 6] = v;
  __syncthreads();
  float s = 0.f;
#pragma unroll
  for (int w = 0; w < 8; ++w) s += red[w];
  return s;
}

// ---------------- V = softmax(V_compress, axis=1) ----------------
__global__ void k_softmaxV(const float* __restrict__ Vc, float* __restrict__ V) {
  int i = threadIdx.x;  // 512 threads, 1 block
  float v0 = Vc[i * 4 + 0], v1 = Vc[i * 4 + 1], v2 = Vc[i * 4 + 2], v3 = Vc[i * 4 + 3];
  float mx = fmaxf(fmaxf(v0, v1), fmaxf(v2, v3));
  float e0 = expf(v0 - mx), e1 = expf(v1 - mx), e2 = expf(v2 - mx), e3 = expf(v3 - mx);
  float s = e0 + e1 + e2 + e3;
  V[i * 4 + 0] = e0 / s; V[i * 4 + 1] = e1 / s; V[i * 4 + 2] = e2 / s; V[i * 4 + 3] = e3 / s;
}

// ---------------- Ws[i][j] = sym tril sigmoid ----------------
__global__ void k_Ws(const float* __restrict__ W, float* __restrict__ Ws) {
  int i = blockIdx.x, j = threadIdx.x;
  float v = 0.f;
  if (i != j) {
    int hi = i > j ? i : j, lo = i > j ? j : i;
    float wv = W[hi * NN + lo];
    v = 1.f / (1.f + expf(-wv));
  }
  Ws[i * NN + j] = v;
}

// ---------------- E sinkhorn: per (i,j) independent 4x4 ----------------
__global__ void k_E(const float* __restrict__ Ec, const float* __restrict__ V,
                    float* __restrict__ E) {
  int idx = blockIdx.x * blockDim.x + threadIdx.x;  // i*512 + j
  if (idx >= NN * NN) return;
  int i = idx >> 9, j = idx & 511;
  float e[16];
  const float* src = Ec + (size_t)idx * 16;
#pragma unroll
  for (int t = 0; t < 16; ++t) e[t] = expf(src[t]);
  float tot = 0.f;
#pragma unroll
  for (int t = 0; t < 16; ++t) tot += e[t];
  float rt = 1.f / tot;
#pragma unroll
  for (int t = 0; t < 16; ++t) e[t] *= rt;
  float Vi[4], Vj[4];
#pragma unroll
  for (int a = 0; a < 4; ++a) { Vi[a] = V[i * 4 + a]; Vj[a] = V[j * 4 + a]; }
#pragma unroll
  for (int it = 0; it < 2; ++it) {
#pragma unroll
    for (int a = 0; a < 4; ++a) {
      float rs = e[a * 4 + 0] + e[a * 4 + 1] + e[a * 4 + 2] + e[a * 4 + 3];
      float sc = Vi[a] / rs;
#pragma unroll
      for (int b = 0; b < 4; ++b) e[a * 4 + b] *= sc;
    }
#pragma unroll
    for (int b = 0; b < 4; ++b) {
      float cs = e[0 + b] + e[4 + b] + e[8 + b] + e[12 + b];
      float sc = Vj[b] / cs;
#pragma unroll
      for (int a = 0; a < 4; ++a) e[a * 4 + b] *= sc;
    }
    float t2 = 0.f;
#pragma unroll
    for (int t = 0; t < 16; ++t) t2 += e[t];
    float rt2 = 1.f / t2;
#pragma unroll
    for (int t = 0; t < 16; ++t) e[t] *= rt2;
  }
  float* dst = E + (size_t)idx * 16;
  bool diag = (i == j);
#pragma unroll
  for (int t = 0; t < 16; ++t) {
    float v = diag ? 0.f : e[t];
    dst[t] = fminf(fmaxf(v, 0.f), 1.f);
  }
}

// ---------------- Pr + sum log(Pr+EPS) ----------------
__global__ __launch_bounds__(512)
void k_Pr(const int* __restrict__ x, const float* __restrict__ V,
          float* __restrict__ Pr, float* __restrict__ logPr) {
  __shared__ float red[8];
  int b = blockIdx.x, i = threadIdx.x;
  int xi = x[b * NN + i];
  float pr = V[i * 4 + xi];
  Pr[b * NN + i] = pr;
  float s = block_reduce_sum_512(logf(pr + EPSF), red);
  if (i == 0) logPr[b] = s;
}

// ---------------- build padded 512x512 Laplacian submatrix ----------------
// rows/cols 0..510 = Lap[1:,1:]+EPS ; row/col 511 = unit padding (det unchanged)
__global__ __launch_bounds__(512)
void k_build(const int* __restrict__ x, const float* __restrict__ Ws,
             const float* __restrict__ E, const float* __restrict__ Pr,
             float* __restrict__ mats, int m0) {
  __shared__ float red[8];
  int slot = blockIdx.y;
  int m = m0 + slot;
  float* A = mats + (size_t)slot * NN * NN;
  int r = blockIdx.x;   // matrix row 0..511
  int j = threadIdx.x;  // original column 0..511
  if (r == NR) {
    A[(size_t)NR * NN + j] = (j == NR) ? 1.f : 0.f;
    return;
  }
  int i = r + 1;  // original row
  float ws = Ws[i * NN + j];
  float wp;
  if (m < BATCH) {
    int xi = x[m * NN + i];
    int xj = x[m * NN + j];
    float e = E[((((size_t)i << 9) + j) << 4) + (xi << 2) + xj];
    float pij = Pr[m * NN + i] * Pr[m * NN + j];
    wp = ws * e / pij;   // ws==0 on diagonal -> wp==0
  } else {
    wp = ws;             // L_0 matrix
  }
  float rowsum = block_reduce_sum_512(wp, red);
  if (j >= 1) A[(size_t)r * NN + (j - 1)] = -wp + ((j == i) ? rowsum : 0.f) + EPSF;
  else        A[(size_t)r * NN + NR] = 0.f;
}

// ---------------- panel factorization: blocked rank-4, column-major LDS ----
// LDS P[c*PS + r]: per-lane accesses P[c*PS + tid] are bank-consecutive
// (conflict-free); U-row reads are float4 broadcasts (free). No register
// arrays -> no scratch spills.
__global__ __launch_bounds__(512)
void k_panel(float* __restrict__ mats, float* __restrict__ ld, int m0, int p) {
  __shared__ float P[64 * PS];  // 132 KB
  int slot = blockIdx.x;
  float* A = mats + (size_t)slot * NN * NN;
  int k0 = p * NB;
  int m = NN - k0;  // panel height
  int tid = threadIdx.x;
  bool own = tid < m;

  // ---- load panel (thread = row, float4 over the 64 columns) ----
  if (own) {
    const float* src = A + (size_t)(k0 + tid) * NN + k0;
#pragma unroll
    for (int c4 = 0; c4 < 16; ++c4) {
      float4 v = *(const float4*)(src + c4 * 4);
      P[(c4 * 4 + 0) * PS + tid] = v.x;
      P[(c4 * 4 + 1) * PS + tid] = v.y;
      P[(c4 * 4 + 2) * PS + tid] = v.z;
      P[(c4 * 4 + 3) * PS + tid] = v.w;
    }
  }
  __syncthreads();

  for (int q = 0; q < 16; ++q) {
    int j0 = q * 4;
    float l0 = 0.f, l1 = 0.f, l2 = 0.f, l3 = 0.f;

    // ---- micro-step 0 (col j0): multipliers + update cols j0+1..j0+3 ----
    {
      float rinv = 1.f / P[j0 * PS + j0];
      if (own && tid > j0) {
        float l = P[j0 * PS + tid] * rinv;
        l0 = l;
        P[j0 * PS + tid] = l;
        P[(j0 + 1) * PS + tid] = fmaf(-l, P[(j0 + 1) * PS + j0], P[(j0 + 1) * PS + tid]);
        P[(j0 + 2) * PS + tid] = fmaf(-l, P[(j0 + 2) * PS + j0], P[(j0 + 2) * PS + tid]);
        P[(j0 + 3) * PS + tid] = fmaf(-l, P[(j0 + 3) * PS + j0], P[(j0 + 3) * PS + tid]);
      }
    }
    __syncthreads();
    // ---- micro-step 1 ----
    {
      int j = j0 + 1;
      float rinv = 1.f / P[j * PS + j];
      if (own && tid > j) {
        float l = P[j * PS + tid] * rinv;
        l1 = l;
        P[j * PS + tid] = l;
        P[(j + 1) * PS + tid] = fmaf(-l, P[(j + 1) * PS + j], P[(j + 1) * PS + tid]);
        P[(j + 2) * PS + tid] = fmaf(-l, P[(j + 2) * PS + j], P[(j + 2) * PS + tid]);
      }
    }
    __syncthreads();
    // ---- micro-step 2 ----
    {
      int j = j0 + 2;
      float rinv = 1.f / P[j * PS + j];
      if (own && tid > j) {
        float l = P[j * PS + tid] * rinv;
        l2 = l;
        P[j * PS + tid] = l;
        P[(j + 1) * PS + tid] = fmaf(-l, P[(j + 1) * PS + j], P[(j + 1) * PS + tid]);
      }
    }
    __syncthreads();
    // ---- micro-step 3 ----
    {
      int j = j0 + 3;
      float rinv = 1.f / P[j * PS + j];
      if (own && tid > j) {
        float l = P[j * PS + tid] * rinv;
        l3 = l;
        P[j * PS + tid] = l;
      }
    }
    __syncthreads();

    // ---- strip solve: rows j0+1..j0+3 of trailing panel cols ----
    // (thread = trailing column; <=60 active, 8-way banked but tiny)
    {
      int c = j0 + 4 + tid;
      if (c < 64) {
        float m10 = P[j0 * PS + (j0 + 1)];
        float m20 = P[j0 * PS + (j0 + 2)];
        float m30 = P[j0 * PS + (j0 + 3)];
        float m21 = P[(j0 + 1) * PS + (j0 + 2)];
        float m31 = P[(j0 + 1) * PS + (j0 + 3)];
        float m32 = P[(j0 + 2) * PS + (j0 + 3)];
        float u0 = P[c * PS + j0];
        float u1 = fmaf(-m10, u0, P[c * PS + j0 + 1]);
        float u2 = fmaf(-m21, u1, fmaf(-m20, u0, P[c * PS + j0 + 2]));
        float u3 = fmaf(-m32, u2, fmaf(-m31, u1, fmaf(-m30, u0, P[c * PS + j0 + 3])));
        P[c * PS + j0 + 1] = u1;
        P[c * PS + j0 + 2] = u2;
        P[c * PS + j0 + 3] = u3;
      }
    }
    __syncthreads();

    // ---- rank-4 bulk update: rows > j0+3, cols j0+4..63 ----
    if (own && tid > j0 + 3) {
      for (int c = j0 + 4; c < 64; ++c) {
        float4 U = *(const float4*)&P[c * PS + j0];  // broadcast (same addr all lanes)
        float v = P[c * PS + tid];
        v = fmaf(-l0, U.x, v);
        v = fmaf(-l1, U.y, v);
        v = fmaf(-l2, U.z, v);
        v = fmaf(-l3, U.w, v);
        P[c * PS + tid] = v;
      }
    }
    __syncthreads();
  }

  // ---- writeback (float4 per row) ----
  if (own) {
    float* dst = A + (size_t)(k0 + tid) * NN + k0;
#pragma unroll
    for (int c4 = 0; c4 < 16; ++c4) {
      float4 v;
      v.x = P[(c4 * 4 + 0) * PS + tid];
      v.y = P[(c4 * 4 + 1) * PS + tid];
      v.z = P[(c4 * 4 + 2) * PS + tid];
      v.w = P[(c4 * 4 + 3) * PS + tid];
      *(float4*)(dst + c4 * 4) = v;
    }
  }

  // ---- partial logdet from pivots (all positive: diagonal dominance) ----
  float lg = 0.f;
  if (tid < 64) lg = logf(P[tid * (PS + 1)]);
#pragma unroll
  for (int off = 32; off > 0; off >>= 1) lg += __shfl_down(lg, off, 64);
  if (tid == 0) {
    int gi = m0 + slot;
    if (p == 0) ld[gi] = lg;
    else        ld[gi] += lg;
  }
}

// ---------------- U12 = L11^{-1} A12 (blocked forward substitution) --------
// thread = column (128 per block, grid.x = col chunks). Columns live in LDS
// C[t*128+tid] (per-lane conflict-free); L11 broadcast at stride 68 (float4-
// aligned). Rank-4 chunks; no barriers in the solve (columns independent).
__global__ __launch_bounds__(128)
void k_u12(float* __restrict__ mats, int p) {
  __shared__ float L11[64 * 68];   // 17.4 KB
  __shared__ float C[64 * 128];    // 32 KB
  int slot = blockIdx.y;
  int k0 = p * NB;
  int w = NN - k0 - NB;
  int cbase = blockIdx.x * 128;
  if (cbase >= w) return;
  int tid = threadIdx.x;
  float* A = mats + (size_t)slot * NN * NN;

  for (int idx = tid; idx < 4096; idx += 128) {
    int r = idx >> 6, c = idx & 63;
    L11[r * 68 + c] = A[(size_t)(k0 + r) * NN + k0 + c];
  }
  int nc = w - cbase; if (nc > 128) nc = 128;
  bool act = tid < nc;
  int col = k0 + NB + cbase + (act ? tid : 0);  // clamped dup for inactive
  for (int t = 0; t < 64; ++t)
    C[t * 128 + tid] = A[(size_t)(k0 + t) * NN + col];
  __syncthreads();

  for (int q = 0; q < 16; ++q) {
    int j0 = q * 4;
    float a0 = C[(j0 + 0) * 128 + tid];
    float a1 = C[(j0 + 1) * 128 + tid];
    float a2 = C[(j0 + 2) * 128 + tid];
    float a3 = C[(j0 + 3) * 128 + tid];
    a1 = fmaf(-L11[(j0 + 1) * 68 + j0], a0, a1);
    a2 = fmaf(-L11[(j0 + 2) * 68 + j0], a0, a2);
    a2 = fmaf(-L11[(j0 + 2) * 68 + j0 + 1], a1, a2);
    a3 = fmaf(-L11[(j0 + 3) * 68 + j0], a0, a3);
    a3 = fmaf(-L11[(j0 + 3) * 68 + j0 + 1], a1, a3);
    a3 = fmaf(-L11[(j0 + 3) * 68 + j0 + 2], a2, a3);
    C[(j0 + 1) * 128 + tid] = a1;
    C[(j0 + 2) * 128 + tid] = a2;
    C[(j0 + 3) * 128 + tid] = a3;
    for (int t = j0 + 4; t < 64; ++t) {
      float4 Lv = *(const float4*)&L11[t * 68 + j0];  // broadcast
      float v = C[t * 128 + tid];
      v = fmaf(-Lv.x, a0, v);
      v = fmaf(-Lv.y, a1, v);
      v = fmaf(-Lv.z, a2, v);
      v = fmaf(-Lv.w, a3, v);
      C[t * 128 + tid] = v;
    }
  }

  if (act) {
    for (int t = 0; t < 64; ++t)
      A[(size_t)(k0 + t) * NN + col] = C[t * 128 + tid];
  }
}

// ---------------- trailing update A22 -= L21 * U12 ----------------
// grid (nt, nt, count), 256 threads, 128x128 tile, k = 64
__global__ __launch_bounds__(256)
void k_gemm(float* __restrict__ mats, int p) {
  __shared__ float At[128 * 65];  // L21 tile, [r][kk], stride 65
  int k0 = p * NB;
  int w = NN - k0 - NB;
  float* A = mats + (size_t)blockIdx.z * NN * NN;
  int rb = blockIdx.x * 128, cb = blockIdx.y * 128;
  int tid = threadIdx.x;
#pragma unroll
  for (int it = 0; it < 32; ++it) {
    int idx = tid + it * 256;
    int r = idx >> 6, kk = idx & 63;
    int gr = rb + r;
    float v = 0.f;
    if (gr < w) v = A[(size_t)(k0 + NB + gr) * NN + k0 + kk];
    At[r * 65 + kk] = v;
  }
  __syncthreads();
  int ty = tid >> 4, tx = tid & 15;
  int r0 = ty * 8, c0 = tx * 8;
  int gc0 = k0 + NB + cb + c0;
  bool cok = (cb + c0) < w;
  float acc[8][8];
#pragma unroll
  for (int q = 0; q < 8; ++q)
#pragma unroll
    for (int u = 0; u < 8; ++u) acc[q][u] = 0.f;
#pragma unroll 4
  for (int kk = 0; kk < 64; ++kk) {
    float la[8];
#pragma unroll
    for (int q = 0; q < 8; ++q) la[q] = At[(r0 + q) * 65 + kk];
    float lb[8];
    if (cok) {
      float4 b0 = *(const float4*)&A[(size_t)(k0 + kk) * NN + gc0];
      float4 b1 = *(const float4*)&A[(size_t)(k0 + kk) * NN + gc0 + 4];
      lb[0] = b0.x; lb[1] = b0.y; lb[2] = b0.z; lb[3] = b0.w;
      lb[4] = b1.x; lb[5] = b1.y; lb[6] = b1.z; lb[7] = b1.w;
    } else {
#pragma unroll
      for (int u = 0; u < 8; ++u) lb[u] = 0.f;
    }
#pragma unroll
    for (int q = 0; q < 8; ++q)
#pragma unroll
      for (int u = 0; u < 8; ++u) acc[q][u] = fmaf(la[q], lb[u], acc[q][u]);
  }
  if (!cok) return;
#pragma unroll
  for (int q = 0; q < 8; ++q) {
    int gr = rb + r0 + q;
    if (gr < w) {
      float* dst = &A[(size_t)(k0 + NB + gr) * NN + gc0];
      float4 v0 = *(const float4*)dst;
      float4 v1 = *(const float4*)(dst + 4);
      v0.x -= acc[q][0]; v0.y -= acc[q][1]; v0.z -= acc[q][2]; v0.w -= acc[q][3];
      v1.x -= acc[q][4]; v1.y -= acc[q][5]; v1.z -= acc[q][6]; v1.w -= acc[q][7];
      *(float4*)dst = v0;
      *(float4*)(dst + 4) = v1;
    }
  }
}

// ---------------- final combine ----------------
__global__ void k_y(const float* __restrict__ logPr, const float* __restrict__ ld,
                    float* __restrict__ y) {
  int b = threadIdx.x;
  if (b < BATCH) y[b] = logPr[b] + ld[b] - ld[BATCH];
}

extern "C" void kernel_launch(void* const* d_in, const int* in_sizes, int n_in,
                              void* d_out, int out_size, void* d_ws, size_t ws_size,
                              hipStream_t stream) {
  const int* x = (const int*)d_in[0];
  const float* W = (const float*)d_in[1];
  const float* Vc = (const float*)d_in[2];
  const float* Ec = (const float*)d_in[3];
  float* out = (float*)d_out;

  char* ws = (char*)d_ws;
  size_t off = 0;
  auto alloc = [&](size_t bytes) -> void* {
    void* pp = ws + off;
    off = (off + bytes + 255) & ~(size_t)255;
    return pp;
  };
  float* V     = (float*)alloc((size_t)NN * 4 * 4);
  float* Wsbuf = (float*)alloc((size_t)NN * NN * 4);
  float* Pr    = (float*)alloc((size_t)BATCH * NN * 4);
  float* logPr = (float*)alloc((size_t)BATCH * 4);
  float* ld    = (float*)alloc((size_t)NMAT * 4);
  float* E     = (float*)alloc((size_t)NN * NN * 16 * 4);
  size_t per_mat = (size_t)NN * NN * 4;
  size_t remain = ws_size > off ? ws_size - off : 0;
  int cap = (int)(remain / per_mat);
  if (cap > NMAT) cap = NMAT;
  if (cap < 1) cap = 1;
  float* mats = (float*)(ws + off);

  k_softmaxV<<<1, 512, 0, stream>>>(Vc, V);
  k_Ws<<<NN, NN, 0, stream>>>(W, Wsbuf);
  k_E<<<(NN * NN) / 256, 256, 0, stream>>>(Ec, V, E);
  k_Pr<<<BATCH, NN, 0, stream>>>(x, V, Pr, logPr);

  for (int m0 = 0; m0 < NMAT; m0 += cap) {
    int cnt = NMAT - m0 < cap ? NMAT - m0 : cap;
    dim3 gb(NN, cnt);
    k_build<<<gb, NN, 0, stream>>>(x, Wsbuf, E, Pr, mats, m0);
    for (int p = 0; p < 8; ++p) {
      k_panel<<<cnt, 512, 0, stream>>>(mats, ld, m0, p);
      int w = NN - p * NB - NB;
      if (w > 0) {
        dim3 gu((w + 127) / 128, cnt);
        k_u12<<<gu, 128, 0, stream>>>(mats, p);
        int nt = (w + 127) / 128;
        dim3 gg(nt, nt, cnt);
        k_gemm<<<gg, 256, 0, stream>>>(mats, p);
      }
    }
  }
  k_y<<<1, 256, 0, stream>>>(logPr, ld, out);
}